// Round 1
// baseline (2311.512 us; speedup 1.0000x reference)
//
#include <hip/hip_runtime.h>
#include <cstdint>
#include <cmath>

typedef __attribute__((ext_vector_type(8))) short short8;   // 8 bf16 (4 VGPRs)
typedef __attribute__((ext_vector_type(4))) float floatx4;  // MFMA C/D

// round-to-nearest-even fp32->bf16, packed pair -> uint (lo = x, hi = y)
__device__ __forceinline__ unsigned pk_bf16(float x, float y) {
    unsigned ux = __float_as_uint(x); ux = ux + 0x7fffu + ((ux >> 16) & 1u);
    unsigned uy = __float_as_uint(y); uy = uy + 0x7fffu + ((uy >> 16) & 1u);
    return (ux >> 16) | (uy & 0xffff0000u);
}
__device__ __forceinline__ unsigned short bf16r(float x) {
    unsigned ux = __float_as_uint(x);
    return (unsigned short)((ux + 0x7fffu + ((ux >> 16) & 1u)) >> 16);
}
__device__ __forceinline__ float bf16d(unsigned short v) {
    return __uint_as_float((unsigned)v << 16);
}

// Raw workgroup barrier with LDS-only drain: __syncthreads() emits
// s_waitcnt vmcnt(0) lgkmcnt(0) before s_barrier, which force-completes the
// X prefetch loads and the fire-and-forget Hout stores on the serial chain
// every step (~1000+ cyc). Only LDS visibility is actually required.
__device__ __forceinline__ void bar_lds() {
    __builtin_amdgcn_sched_barrier(0);
    asm volatile("s_waitcnt lgkmcnt(0)" ::: "memory");
    __builtin_amdgcn_s_barrier();
    __builtin_amdgcn_sched_barrier(0);
}

// ---------------------------------------------------------------------------
// Kernel 1: fused embedding gather + input projections via bf16 MFMA.
// (unchanged from r17: A-tile staged once, W streamed from L2 over 16 j-tiles)
// ---------------------------------------------------------------------------
__global__ __launch_bounds__(256) void proj_kernel(
    const int* __restrict__ word_ids, const float* __restrict__ embed,
    const float* __restrict__ w_ih_f, const float* __restrict__ b_f,
    const float* __restrict__ w_ih_b, const float* __restrict__ b_b,
    unsigned short* __restrict__ XF, unsigned short* __restrict__ XB,
    int t0, int lgL)
{
    __shared__ unsigned short As[64][264];   // 64 x 256 bf16, +8 pad
    __shared__ unsigned short Bs[64][264];
    __shared__ int idx[64];

    const int tid = threadIdx.x;
    const int nt  = blockIdx.x;   // 0..L-1 (n tile; n = b*L + tl)
    const int dir = blockIdx.y;   // 0..1
    const int Lm1 = (1 << lgL) - 1;
    const float* __restrict__ W    = dir ? w_ih_b : w_ih_f;
    const float* __restrict__ bias = dir ? b_b : b_f;
    unsigned short* __restrict__ Xout = dir ? XB : XF;

    if (tid < 64) {
        int n  = nt * 64 + tid;
        int b  = n >> lgL;
        int tl = n & Lm1;
        int tg = dir ? (511 - (t0 + tl)) : (t0 + tl);
        idx[tid] = word_ids[b * 512 + tg];
    }
    __syncthreads();

    // stage A (embedding rows) once: 64 rows x 256 cols, bf16
    #pragma unroll
    for (int i = 0; i < 16; ++i) {
        int flat = i * 256 + tid;        // 0..4095 float4 units
        int r  = flat >> 6;              // row 0..63
        int kq = flat & 63;              // k = kq*4
        floatx4 a = *(const floatx4*)&embed[(size_t)idx[r] * 256 + kq * 4];
        *(uint2*)&As[r][kq * 4] = make_uint2(pk_bf16(a.x, a.y), pk_bf16(a.z, a.w));
    }
    __syncthreads();

    const int w    = tid >> 6;     // wave 0..3: n-rows [w*16, w*16+16)
    const int lane = tid & 63;
    const int q    = lane >> 4;    // k-quad
    const int lr   = lane & 15;

    // A-fragments in registers, reused across all 16 j-tiles
    short8 af[8];
    #pragma unroll
    for (int ks = 0; ks < 8; ++ks)
        af[ks] = *(const short8*)&As[w * 16 + lr][ks * 32 + q * 8];

    // n -> (b, tl) mapping for this thread's output rows (fixed across jt)
    int bb[4], tt4[4];
    #pragma unroll
    for (int reg = 0; reg < 4; ++reg) {
        int n  = nt * 64 + w * 16 + q * 4 + reg;
        bb[reg]  = n >> lgL;
        tt4[reg] = n & Lm1;
    }

    for (int jt = 0; jt < 16; ++jt) {
        __syncthreads();   // previous jt's Bs reads complete
        #pragma unroll
        for (int i = 0; i < 16; ++i) {
            int flat = i * 256 + tid;
            int r  = flat >> 6;
            int kq = flat & 63;
            floatx4 wv = *(const floatx4*)&W[(size_t)(jt * 64 + r) * 256 + kq * 4];
            *(uint2*)&Bs[r][kq * 4] = make_uint2(pk_bf16(wv.x, wv.y), pk_bf16(wv.z, wv.w));
        }
        __syncthreads();   // Bs staged

        #pragma unroll
        for (int jt4 = 0; jt4 < 4; ++jt4) {
            floatx4 c = {0.f, 0.f, 0.f, 0.f};
            #pragma unroll
            for (int ks = 0; ks < 8; ++ks) {
                short8 bf = *(const short8*)&Bs[jt4 * 16 + lr][ks * 32 + q * 8];
                c = __builtin_amdgcn_mfma_f32_16x16x32_bf16(af[ks], bf, c, 0, 0, 0);
            }
            int j = jt * 64 + jt4 * 16 + lr;
            float bj = bias[j];
            #pragma unroll
            for (int reg = 0; reg < 4; ++reg)
                Xout[((size_t)tt4[reg] * 64 + bb[reg]) * 1024 + j] = bf16r(c[reg] + bj);
        }
    }
}

// ---------------------------------------------------------------------------
// Kernel 2: BiLSTM scan — r18 RESTRUCTURE (unit-major waves).
// Old structure (r16): wave = (gate, unit-half); the 4 gates of a unit landed
// in 4 waves -> scr LDS round-trip + 2 __syncthreads per step, each draining
// vmcnt(0) (X prefetch + Hout stores) on the serial chain: 2.05 us/step with
// MfmaUtil 10%.
// New structure: wave w owns units [w*32, w*32+32) x ALL 4 gates (8 N-tiles,
// same 64 MFMAs/wave/step, same fragments & ks order -> bitwise-identical h).
// i/f/g/o for a unit land in the same lane's accumulators (C: col=lr=unit,
// row=reg=batch at q==0) -> activations fully in-register, scr deleted,
// ONE raw barrier per step (lgkmcnt-only drain), Ah double-buffered by step
// parity to replace the second barrier's anti-dependency protection.
// ---------------------------------------------------------------------------
__global__ __launch_bounds__(512, 1)
__attribute__((amdgpu_num_vgpr(256)))
void lstm_scan(
    const unsigned short* __restrict__ XF, const unsigned short* __restrict__ XB,
    const float* __restrict__ w_hh_f, const float* __restrict__ w_hh_b,
    float* __restrict__ hf, float* __restrict__ hb,
    float* __restrict__ state_c, float* __restrict__ state_h, int t0, int t1)
{
    __shared__ unsigned short Ah[2][2][264];   // [parity][batch][unit] bf16
    __shared__ short8 Wlds[8 * 2 * 8 * 64];    // [wave][lds-tile][ks][lane] = 128 KB

    const int blk = blockIdx.x;      // 0..63
    const int dir = blk >> 5;
    const int grp = blk & 31;
    const int B0  = grp * 2;
    const unsigned short* __restrict__ X = dir ? XB : XF;
    const float* __restrict__ Whh = dir ? w_hh_b : w_hh_f;
    float* __restrict__ Hout      = dir ? hb : hf;

    const int tid  = threadIdx.x;    // 0..511
    const int w    = tid >> 6;       // wave 0..7: units [w*32, w*32+32)
    const int lane = tid & 63;
    const int q    = lane >> 4;
    const int lr   = lane & 15;
    const int u0   = w * 32 + lr;    // +ut*16 for the second unit tile

    // ---- stage W_hh as bf16 B-fragments for this wave's 8 N-tiles:
    // nt = gt*2+ut -> row j = gt*256 + w*32 + ut*16 + lr. Tiles 0-5 -> regs
    // (AGPR-backed), 6-7 -> LDS.
    short8 wreg[6][8];
    #pragma unroll
    for (int nt = 0; nt < 8; ++nt) {
        const int gt = nt >> 1, ut = nt & 1;
        const float* wrow = &Whh[(size_t)(gt * 256 + w * 32 + ut * 16 + lr) * 256];
        #pragma unroll
        for (int ks = 0; ks < 8; ++ks) {
            floatx4 a = *(const floatx4*)&wrow[ks * 32 + q * 8];
            floatx4 b = *(const floatx4*)&wrow[ks * 32 + q * 8 + 4];
            union { uint4 u4; short8 s; } cv;
            cv.u4 = make_uint4(pk_bf16(a.x, a.y), pk_bf16(a.z, a.w),
                               pk_bf16(b.x, b.y), pk_bf16(b.z, b.w));
            if (nt < 6) wreg[nt][ks] = cv.s;
            else        Wlds[((w * 2 + (nt - 6)) * 8 + ks) * 64 + lane] = cv.s;
        }
    }

    // ---- chain state: q==0 lanes own (batch b, unit-tile ut) x 4
    float cst[2][2] = {{0.f, 0.f}, {0.f, 0.f}};
    float hl [2][2] = {{0.f, 0.f}, {0.f, 0.f}};
    float xg [4][2][2];   // [gate][b][ut], prefetched one step ahead

    if (q == 0) {
        if (t0 != 0) {
            #pragma unroll
            for (int b = 0; b < 2; ++b)
                #pragma unroll
                for (int ut = 0; ut < 2; ++ut) {
                    int sgi = (dir * 64 + B0 + b) * 256 + u0 + ut * 16;
                    cst[b][ut] = state_c[sgi];
                    hl [b][ut] = state_h[sgi];
                }
        }
        #pragma unroll
        for (int b = 0; b < 2; ++b)
            #pragma unroll
            for (int ut = 0; ut < 2; ++ut)
                Ah[t0 & 1][b][u0 + ut * 16] = bf16r(hl[b][ut]);
        // prefetch X for the first step
        #pragma unroll
        for (int gg = 0; gg < 4; ++gg)
            #pragma unroll
            for (int b = 0; b < 2; ++b)
                #pragma unroll
                for (int ut = 0; ut < 2; ++ut)
                    xg[gg][b][ut] = bf16d(
                        X[((size_t)(B0 + b)) * 1024 + gg * 256 + u0 + ut * 16]);
    }
    bar_lds();   // Wlds + Ah[t0&1] visible

    const floatx4 zero = {0.f, 0.f, 0.f, 0.f};

    for (int t = t0; t < t1; ++t) {
        const int p = t & 1;

        // phase A: c[gt][ut] = h(t-1) @ Whh^T tile — ks-outer, 8 independent
        // accumulator chains inner for pipelining; af fragment read on the fly.
        floatx4 c[4][2];
        #pragma unroll
        for (int gt = 0; gt < 4; ++gt) { c[gt][0] = zero; c[gt][1] = zero; }
        #pragma unroll
        for (int ks = 0; ks < 8; ++ks) {
            short8 af = *(const short8*)&Ah[p][lr & 1][ks * 32 + q * 8];
            #pragma unroll
            for (int nt = 0; nt < 8; ++nt) {
                const int gt = nt >> 1, ut = nt & 1;
                short8 bf = (nt < 6) ? wreg[nt][ks]
                                     : Wlds[((w * 2 + (nt - 6)) * 8 + ks) * 64 + lane];
                c[gt][ut] = __builtin_amdgcn_mfma_f32_16x16x32_bf16(af, bf, c[gt][ut], 0, 0, 0);
            }
        }

        // phase B: in-register activations on q==0 lanes (row=reg=batch, col=lr)
        if (q == 0) {
            #pragma unroll
            for (int b = 0; b < 2; ++b)
                #pragma unroll
                for (int ut = 0; ut < 2; ++ut) {
                    float gi = c[0][ut][b] + xg[0][b][ut];
                    float gf = c[1][ut][b] + xg[1][b][ut];
                    float gv = c[2][ut][b] + xg[2][b][ut];
                    float go = c[3][ut][b] + xg[3][b][ut];
                    float ig = 1.f / (1.f + expf(-gi));
                    float fg = 1.f / (1.f + expf(-gf));
                    float gc = tanhf(gv);
                    float og = 1.f / (1.f + expf(-go));
                    float cs = fg * cst[b][ut] + ig * gc;
                    cst[b][ut] = cs;
                    float h = og * tanhf(cs);
                    hl[b][ut] = h;
                    Ah[p ^ 1][b][u0 + ut * 16] = bf16r(h);
                    int tt = dir ? (511 - t) : t;
                    Hout[((size_t)tt * 64 + B0 + b) * 256 + u0 + ut * 16] = h;
                }
            // prefetch X for next step — stays in flight across the raw
            // barrier (no vmcnt drain), hidden under next step's MFMA phase
            int tn = (t + 1 < t1) ? (t + 1 - t0) : 0;
            #pragma unroll
            for (int gg = 0; gg < 4; ++gg)
                #pragma unroll
                for (int b = 0; b < 2; ++b)
                    #pragma unroll
                    for (int ut = 0; ut < 2; ++ut)
                        xg[gg][b][ut] = bf16d(
                            X[((size_t)tn * 64 + B0 + b) * 1024 + gg * 256 + u0 + ut * 16]);
        }
        bar_lds();   // Ah[p^1] visible; own Ah[p] reads drained
    }

    if (q == 0) {
        #pragma unroll
        for (int b = 0; b < 2; ++b)
            #pragma unroll
            for (int ut = 0; ut < 2; ++ut) {
                int sgi = (dir * 64 + B0 + b) * 256 + u0 + ut * 16;
                state_c[sgi] = cst[b][ut];
                state_h[sgi] = hl[b][ut];
            }
    }
}

// ---------------------------------------------------------------------------
// Kernel 3: LayerNorm + classifier + argmax. One wave per (b,t).
// ---------------------------------------------------------------------------
__global__ __launch_bounds__(256) void ln_cls_kernel(
    const float* __restrict__ hf, const float* __restrict__ hb,
    const float* __restrict__ gamma, const float* __restrict__ beta,
    const float* __restrict__ cls_w, const float* __restrict__ cls_b,
    float* __restrict__ logits, float* __restrict__ dout)
{
    const int lane = threadIdx.x & 63;
    const int wid  = threadIdx.x >> 6;
    const int pos  = blockIdx.x * 4 + wid;   // 0..32767
    const int b = pos >> 9;
    const int t = pos & 511;

    float4 v0 = *(const float4*)&hf[((size_t)t * 64 + b) * 256 + lane * 4];
    float4 v1 = *(const float4*)&hb[((size_t)t * 64 + b) * 256 + lane * 4];
    float x[8] = {v0.x, v0.y, v0.z, v0.w, v1.x, v1.y, v1.z, v1.w};

    float s = 0.f;
    #pragma unroll
    for (int i = 0; i < 8; ++i) s += x[i];
    #pragma unroll
    for (int off = 32; off > 0; off >>= 1) s += __shfl_xor(s, off, 64);
    float mu = s * (1.f / 512.f);

    float d[8];
    float sq = 0.f;
    #pragma unroll
    for (int i = 0; i < 8; ++i) { d[i] = x[i] - mu; sq += d[i] * d[i]; }
    #pragma unroll
    for (int off = 32; off > 0; off >>= 1) sq += __shfl_xor(sq, off, 64);
    float rs = 1.f / sqrtf(sq * (1.f / 512.f) + 1e-5f);

    float4 g0  = *(const float4*)&gamma[lane * 4];
    float4 g1  = *(const float4*)&gamma[256 + lane * 4];
    float4 be0 = *(const float4*)&beta[lane * 4];
    float4 be1 = *(const float4*)&beta[256 + lane * 4];
    float y[8];
    y[0] = d[0] * rs * g0.x + be0.x; y[1] = d[1] * rs * g0.y + be0.y;
    y[2] = d[2] * rs * g0.z + be0.z; y[3] = d[3] * rs * g0.w + be0.w;
    y[4] = d[4] * rs * g1.x + be1.x; y[5] = d[5] * rs * g1.y + be1.y;
    y[6] = d[6] * rs * g1.z + be1.z; y[7] = d[7] * rs * g1.w + be1.w;

    float lgt[9];
    #pragma unroll
    for (int c = 0; c < 9; ++c) {
        float4 w0 = *(const float4*)&cls_w[c * 512 + lane * 4];
        float4 w1 = *(const float4*)&cls_w[c * 512 + 256 + lane * 4];
        float p = y[0] * w0.x + y[1] * w0.y + y[2] * w0.z + y[3] * w0.w
                + y[4] * w1.x + y[5] * w1.y + y[6] * w1.z + y[7] * w1.w;
        #pragma unroll
        for (int off = 32; off > 0; off >>= 1) p += __shfl_xor(p, off, 64);
        lgt[c] = p + cls_b[c];
    }
    if (lane == 0) {
        int bestc = 0;
        float bestv = lgt[0];
        #pragma unroll
        for (int c = 1; c < 9; ++c)
            if (lgt[c] > bestv) { bestv = lgt[c]; bestc = c; }  // strict >: first max
        dout[1 + pos] = (float)bestc;
        #pragma unroll
        for (int c = 0; c < 9; ++c) logits[(size_t)pos * 9 + c] = lgt[c];
    }
}

// ---------------------------------------------------------------------------
// Kernel 4: CRF numerator + forward algorithm (logZ). One wave per batch row.
// ---------------------------------------------------------------------------
__global__ __launch_bounds__(64) void crf_kernel(
    const float* __restrict__ logits, const int* __restrict__ label_ids,
    const float* __restrict__ crf_start, const float* __restrict__ crf_end,
    const float* __restrict__ crf_trans, float* __restrict__ llh)
{
    __shared__ float Ts[9][12];
    const int b = blockIdx.x;
    const int lane = threadIdx.x;
    if (lane < 81) Ts[lane / 9][lane % 9] = crf_trans[lane];
    __syncthreads();

    const float* __restrict__ em  = &logits[(size_t)b * 512 * 9];
    const int* __restrict__ tags  = &label_ids[b * 512];

    float part = 0.f;
    for (int t = lane; t < 512; t += 64) {
        int tg = tags[t];
        part += em[t * 9 + tg];
        if (t < 511) part += Ts[tg][tags[t + 1]];
    }
    #pragma unroll
    for (int off = 32; off > 0; off >>= 1) part += __shfl_xor(part, off, 64);
    float numer = part + crf_start[tags[0]] + crf_end[tags[511]];

    const int j = (lane < 9) ? lane : 0;
    float alpha = crf_start[j] + em[j];
    for (int t = 1; t < 512; ++t) {
        float av[9];
        float m = -1e30f;
        #pragma unroll
        for (int i = 0; i < 9; ++i) {
            float ai = __shfl(alpha, i, 64);
            av[i] = ai + Ts[i][j];
            m = fmaxf(m, av[i]);
        }
        float ssum = 0.f;
        #pragma unroll
        for (int i = 0; i < 9; ++i) ssum += expf(av[i] - m);
        alpha = m + logf(ssum) + em[t * 9 + j];
    }
    float v = (lane < 9) ? (alpha + crf_end[j]) : -1e30f;
    float mm = v;
    #pragma unroll
    for (int off = 32; off > 0; off >>= 1) mm = fmaxf(mm, __shfl_xor(mm, off, 64));
    float es = (lane < 9) ? expf(v - mm) : 0.f;
    #pragma unroll
    for (int off = 32; off > 0; off >>= 1) es += __shfl_xor(es, off, 64);
    if (lane == 0) llh[b] = numer - (mm + logf(es));
}

// ---------------------------------------------------------------------------
// Kernel 5: loss = -sum_b llh[b]
// ---------------------------------------------------------------------------
__global__ __launch_bounds__(64) void final_reduce(
    const float* __restrict__ llh, float* __restrict__ dout)
{
    float v = llh[threadIdx.x];
    #pragma unroll
    for (int off = 32; off > 0; off >>= 1) v += __shfl_xor(v, off, 64);
    if (threadIdx.x == 0) dout[0] = -v;
}

// ---------------------------------------------------------------------------
extern "C" void kernel_launch(void* const* d_in, const int* in_sizes, int n_in,
                              void* d_out, int out_size, void* d_ws, size_t ws_size,
                              hipStream_t stream)
{
    const int*   word_ids  = (const int*)d_in[0];
    const int*   label_ids = (const int*)d_in[1];
    const float* embed     = (const float*)d_in[2];
    const float* w_ih_f    = (const float*)d_in[3];
    const float* w_hh_f    = (const float*)d_in[4];
    const float* b_f       = (const float*)d_in[5];
    const float* w_ih_b    = (const float*)d_in[6];
    const float* w_hh_b    = (const float*)d_in[7];
    const float* b_b       = (const float*)d_in[8];
    const float* ln_gamma  = (const float*)d_in[9];
    const float* ln_beta   = (const float*)d_in[10];
    const float* cls_w     = (const float*)d_in[11];
    const float* cls_b     = (const float*)d_in[12];
    const float* crf_start = (const float*)d_in[13];
    const float* crf_end   = (const float*)d_in[14];
    const float* crf_trans = (const float*)d_in[15];

    char* w = (char*)d_ws;
    auto alloc = [&](size_t bytes) -> char* {
        char* p = w; w += (bytes + 255) & ~(size_t)255; return p;
    };
    float* hf      = (float*)alloc((size_t)8388608 * 4);   // [512][64][256]
    float* hb      = (float*)alloc((size_t)8388608 * 4);
    float* logits  = (float*)alloc((size_t)294912 * 4);    // [B*T][9]
    float* state_c = (float*)alloc((size_t)32768 * 4);     // [dir][64][256]
    float* state_h = (float*)alloc((size_t)32768 * 4);
    float* llh     = (float*)alloc((size_t)64 * 4);
    size_t fixed   = (size_t)(w - (char*)d_ws);

    // choose largest time-chunk L whose bf16 X buffers fit (L=512 expected)
    int L = 512;
    while (L > 32 && fixed + (size_t)L * 262144 > ws_size) L >>= 1;
    unsigned short* XF = (unsigned short*)alloc((size_t)L * 65536 * 2);  // [L][64][1024] bf16
    unsigned short* XB = (unsigned short*)alloc((size_t)L * 65536 * 2);
    int lgL = 31 - __builtin_clz((unsigned)L);

    for (int t0 = 0; t0 < 512; t0 += L) {
        proj_kernel<<<dim3(L, 2), 256, 0, stream>>>(
            word_ids, embed, w_ih_f, b_f, w_ih_b, b_b, XF, XB, t0, lgL);
        lstm_scan<<<64, 512, 0, stream>>>(
            XF, XB, w_hh_f, w_hh_b, hf, hb, state_c, state_h, t0, t0 + L);
    }
    ln_cls_kernel<<<8192, 256, 0, stream>>>(
        hf, hb, ln_gamma, ln_beta, cls_w, cls_b, logits, (float*)d_out);
    crf_kernel<<<64, 64, 0, stream>>>(
        logits, label_ids, crf_start, crf_end, crf_trans, llh);
    final_reduce<<<1, 64, 0, stream>>>(llh, (float*)d_out);
}

// Round 2
// 1362.878 us; speedup vs baseline: 1.6961x; 1.6961x over previous
//
#include <hip/hip_runtime.h>
#include <cstdint>
#include <cmath>

typedef __attribute__((ext_vector_type(8))) short short8;   // 8 bf16 (4 VGPRs)
typedef __attribute__((ext_vector_type(4))) float floatx4;  // MFMA C/D

// round-to-nearest-even fp32->bf16, packed pair -> uint (lo = x, hi = y)
__device__ __forceinline__ unsigned pk_bf16(float x, float y) {
    unsigned ux = __float_as_uint(x); ux = ux + 0x7fffu + ((ux >> 16) & 1u);
    unsigned uy = __float_as_uint(y); uy = uy + 0x7fffu + ((uy >> 16) & 1u);
    return (ux >> 16) | (uy & 0xffff0000u);
}
__device__ __forceinline__ unsigned short bf16r(float x) {
    unsigned ux = __float_as_uint(x);
    return (unsigned short)((ux + 0x7fffu + ((ux >> 16) & 1u)) >> 16);
}
__device__ __forceinline__ float bf16d(unsigned short v) {
    return __uint_as_float((unsigned)v << 16);
}

// Raw workgroup barrier with LDS-only drain: __syncthreads() emits
// s_waitcnt vmcnt(0) lgkmcnt(0) before s_barrier, which would force-complete
// the X prefetch loads and the fire-and-forget Hout stores on the serial
// chain every step. Only LDS visibility is actually required.
__device__ __forceinline__ void bar_lds() {
    __builtin_amdgcn_sched_barrier(0);
    asm volatile("s_waitcnt lgkmcnt(0)" ::: "memory");
    __builtin_amdgcn_s_barrier();
    __builtin_amdgcn_sched_barrier(0);
}

// ---------------------------------------------------------------------------
// Kernel 1: fused embedding gather + input projections via bf16 MFMA.
// (unchanged: A-tile staged once, W streamed from L2 over 16 j-tiles)
// ---------------------------------------------------------------------------
__global__ __launch_bounds__(256) void proj_kernel(
    const int* __restrict__ word_ids, const float* __restrict__ embed,
    const float* __restrict__ w_ih_f, const float* __restrict__ b_f,
    const float* __restrict__ w_ih_b, const float* __restrict__ b_b,
    unsigned short* __restrict__ XF, unsigned short* __restrict__ XB,
    int t0, int lgL)
{
    __shared__ unsigned short As[64][264];   // 64 x 256 bf16, +8 pad
    __shared__ unsigned short Bs[64][264];
    __shared__ int idx[64];

    const int tid = threadIdx.x;
    const int nt  = blockIdx.x;   // 0..L-1 (n tile; n = b*L + tl)
    const int dir = blockIdx.y;   // 0..1
    const int Lm1 = (1 << lgL) - 1;
    const float* __restrict__ W    = dir ? w_ih_b : w_ih_f;
    const float* __restrict__ bias = dir ? b_b : b_f;
    unsigned short* __restrict__ Xout = dir ? XB : XF;

    if (tid < 64) {
        int n  = nt * 64 + tid;
        int b  = n >> lgL;
        int tl = n & Lm1;
        int tg = dir ? (511 - (t0 + tl)) : (t0 + tl);
        idx[tid] = word_ids[b * 512 + tg];
    }
    __syncthreads();

    // stage A (embedding rows) once: 64 rows x 256 cols, bf16
    #pragma unroll
    for (int i = 0; i < 16; ++i) {
        int flat = i * 256 + tid;        // 0..4095 float4 units
        int r  = flat >> 6;              // row 0..63
        int kq = flat & 63;              // k = kq*4
        floatx4 a = *(const floatx4*)&embed[(size_t)idx[r] * 256 + kq * 4];
        *(uint2*)&As[r][kq * 4] = make_uint2(pk_bf16(a.x, a.y), pk_bf16(a.z, a.w));
    }
    __syncthreads();

    const int w    = tid >> 6;     // wave 0..3: n-rows [w*16, w*16+16)
    const int lane = tid & 63;
    const int q    = lane >> 4;    // k-quad
    const int lr   = lane & 15;

    // A-fragments in registers, reused across all 16 j-tiles
    short8 af[8];
    #pragma unroll
    for (int ks = 0; ks < 8; ++ks)
        af[ks] = *(const short8*)&As[w * 16 + lr][ks * 32 + q * 8];

    // n -> (b, tl) mapping for this thread's output rows (fixed across jt)
    int bb[4], tt4[4];
    #pragma unroll
    for (int reg = 0; reg < 4; ++reg) {
        int n  = nt * 64 + w * 16 + q * 4 + reg;
        bb[reg]  = n >> lgL;
        tt4[reg] = n & Lm1;
    }

    for (int jt = 0; jt < 16; ++jt) {
        __syncthreads();   // previous jt's Bs reads complete
        #pragma unroll
        for (int i = 0; i < 16; ++i) {
            int flat = i * 256 + tid;
            int r  = flat >> 6;
            int kq = flat & 63;
            floatx4 wv = *(const floatx4*)&W[(size_t)(jt * 64 + r) * 256 + kq * 4];
            *(uint2*)&Bs[r][kq * 4] = make_uint2(pk_bf16(wv.x, wv.y), pk_bf16(wv.z, wv.w));
        }
        __syncthreads();   // Bs staged

        #pragma unroll
        for (int jt4 = 0; jt4 < 4; ++jt4) {
            floatx4 c = {0.f, 0.f, 0.f, 0.f};
            #pragma unroll
            for (int ks = 0; ks < 8; ++ks) {
                short8 bf = *(const short8*)&Bs[jt4 * 16 + lr][ks * 32 + q * 8];
                c = __builtin_amdgcn_mfma_f32_16x16x32_bf16(af[ks], bf, c, 0, 0, 0);
            }
            int j = jt * 64 + jt4 * 16 + lr;
            float bj = bias[j];
            #pragma unroll
            for (int reg = 0; reg < 4; ++reg)
                Xout[((size_t)tt4[reg] * 64 + bb[reg]) * 1024 + j] = bf16r(c[reg] + bj);
        }
    }
}

// ---------------------------------------------------------------------------
// Kernel 2: BiLSTM scan — r19.
// r18 post-mortem: unit-major waves + single barrier were right, but phase B
// ran on q==0 lanes only (4x TRANS-pipe serialization -> VALUBusy 7.5->12.1%)
// and per-lane state (xg[16]+cst[4]+hl[4]) blew the 256-reg budget (WRITE_SIZE
// +5.2MB = spill traffic). r19: after the MFMA phase, redistribute the gate
// preacts WITHIN each wave via 16 __shfl + selects so every lane owns exactly
// one (batch, unit) pair -- full 512-thread activation parallelism, no LDS
// scr, no second barrier, per-lane state back to xg[4]+cst+hl.
// Arithmetic (MFMA fragments, ks order, f32 activation) is bitwise identical.
// ---------------------------------------------------------------------------
__global__ __launch_bounds__(512, 1)
__attribute__((amdgpu_num_vgpr(256)))
void lstm_scan(
    const unsigned short* __restrict__ XF, const unsigned short* __restrict__ XB,
    const float* __restrict__ w_hh_f, const float* __restrict__ w_hh_b,
    float* __restrict__ hf, float* __restrict__ hb,
    float* __restrict__ state_c, float* __restrict__ state_h, int t0, int t1)
{
    __shared__ unsigned short Ah[2][2][264];   // [parity][batch][unit] bf16
    __shared__ short8 Wlds[8 * 2 * 8 * 64];    // [wave][lds-tile][ks][lane] = 128 KB

    const int blk = blockIdx.x;      // 0..63
    const int dir = blk >> 5;
    const int grp = blk & 31;
    const int B0  = grp * 2;
    const unsigned short* __restrict__ X = dir ? XB : XF;
    const float* __restrict__ Whh = dir ? w_hh_b : w_hh_f;
    float* __restrict__ Hout      = dir ? hb : hf;

    const int tid  = threadIdx.x;    // 0..511
    const int w    = tid >> 6;       // wave 0..7: units [w*32, w*32+32)
    const int lane = tid & 63;
    const int q    = lane >> 4;
    const int lr   = lane & 15;

    // ---- stage W_hh as bf16 B-fragments for this wave's 8 N-tiles:
    // nt = gt*2+ut -> row j = gt*256 + w*32 + ut*16 + lr. Tiles 0-5 -> regs,
    // 6-7 -> LDS.
    short8 wreg[6][8];
    #pragma unroll
    for (int nt = 0; nt < 8; ++nt) {
        const int gt = nt >> 1, ut = nt & 1;
        const float* wrow = &Whh[(size_t)(gt * 256 + w * 32 + ut * 16 + lr) * 256];
        #pragma unroll
        for (int ks = 0; ks < 8; ++ks) {
            floatx4 a = *(const floatx4*)&wrow[ks * 32 + q * 8];
            floatx4 b = *(const floatx4*)&wrow[ks * 32 + q * 8 + 4];
            union { uint4 u4; short8 s; } cv;
            cv.u4 = make_uint4(pk_bf16(a.x, a.y), pk_bf16(a.z, a.w),
                               pk_bf16(b.x, b.y), pk_bf16(b.z, b.w));
            if (nt < 6) wreg[nt][ks] = cv.s;
            else        Wlds[((w * 2 + (nt - 6)) * 8 + ks) * 64 + lane] = cv.s;
        }
    }

    // ---- per-lane chain state: lane L owns (batch = L>>5, unit = w*32+(L&31))
    const int b_own = lane >> 5;
    const int u_own = w * 32 + (lane & 31);
    const int sgi   = (dir * 64 + B0 + b_own) * 256 + u_own;

    float cst = 0.f, hlast = 0.f;
    if (t0 != 0) { cst = state_c[sgi]; hlast = state_h[sgi]; }
    Ah[t0 & 1][b_own][u_own] = bf16r(hlast);

    float xg[4];   // X preacts for the CURRENT step, prefetched one step ahead
    {
        const unsigned short* Xc = &X[((size_t)(B0 + b_own)) * 1024 + u_own];
        #pragma unroll
        for (int gg = 0; gg < 4; ++gg) xg[gg] = bf16d(Xc[gg * 256]);
    }
    bar_lds();   // Wlds + Ah[t0&1] visible

    const floatx4 zero = {0.f, 0.f, 0.f, 0.f};
    const int srcl = lane & 15;
    const int sel  = lane >> 4;     // = b*2 + ut of the pair this lane owns

    for (int t = t0; t < t1; ++t) {
        const int p = t & 1;

        // phase A: c[gt][ut] = h(t-1) @ Whh^T tile — ks-outer, 8 independent
        // accumulator chains inner; af fragment read on the fly.
        floatx4 c[4][2];
        #pragma unroll
        for (int gt = 0; gt < 4; ++gt) { c[gt][0] = zero; c[gt][1] = zero; }
        #pragma unroll
        for (int ks = 0; ks < 8; ++ks) {
            short8 af = *(const short8*)&Ah[p][lr & 1][ks * 32 + q * 8];
            #pragma unroll
            for (int nt = 0; nt < 8; ++nt) {
                const int gt = nt >> 1, ut = nt & 1;
                short8 bf = (nt < 6) ? wreg[nt][ks]
                                     : Wlds[((w * 2 + (nt - 6)) * 8 + ks) * 64 + lane];
                c[gt][ut] = __builtin_amdgcn_mfma_f32_16x16x32_bf16(af, bf, c[gt][ut], 0, 0, 0);
            }
        }

        // redistribute gate preacts within the wave: MFMA C layout puts
        // (batch b=reg, unit=lr) on q==0 lanes; shuffle so lane L gets the
        // (b,ut) matching sel = L>>4 at unit lr = L&15.
        float gsum[4];
        #pragma unroll
        for (int gt = 0; gt < 4; ++gt) {
            float s0 = __shfl(c[gt][0][0], srcl, 64);   // ut=0, b=0
            float s1 = __shfl(c[gt][1][0], srcl, 64);   // ut=1, b=0
            float s2 = __shfl(c[gt][0][1], srcl, 64);   // ut=0, b=1
            float s3 = __shfl(c[gt][1][1], srcl, 64);   // ut=1, b=1
            float v01 = (sel & 1) ? s1 : s0;
            float v23 = (sel & 1) ? s3 : s2;
            gsum[gt] = ((sel & 2) ? v23 : v01) + xg[gt];
        }

        // prefetch X for next step — stays in flight across the raw barrier
        // (no vmcnt drain), hidden under next step's MFMA phase
        {
            int tn = (t + 1 < t1) ? (t + 1 - t0) : 0;
            const unsigned short* Xc = &X[((size_t)tn * 64 + B0 + b_own) * 1024 + u_own];
            #pragma unroll
            for (int gg = 0; gg < 4; ++gg) xg[gg] = bf16d(Xc[gg * 256]);
        }

        // phase B: one (batch, unit) pair per lane — full parallelism
        {
            float ig = 1.f / (1.f + expf(-gsum[0]));
            float fg = 1.f / (1.f + expf(-gsum[1]));
            float gc = tanhf(gsum[2]);
            float og = 1.f / (1.f + expf(-gsum[3]));
            cst = fg * cst + ig * gc;
            float h = og * tanhf(cst);
            hlast = h;
            Ah[p ^ 1][b_own][u_own] = bf16r(h);
            int tt = dir ? (511 - t) : t;
            Hout[((size_t)tt * 64 + B0 + b_own) * 256 + u_own] = h;
        }
        bar_lds();   // Ah[p^1] visible; own Ah[p] reads drained
    }

    state_c[sgi] = cst;
    state_h[sgi] = hlast;
}

// ---------------------------------------------------------------------------
// Kernel 3: LayerNorm + classifier + argmax. One wave per (b,t).
// ---------------------------------------------------------------------------
__global__ __launch_bounds__(256) void ln_cls_kernel(
    const float* __restrict__ hf, const float* __restrict__ hb,
    const float* __restrict__ gamma, const float* __restrict__ beta,
    const float* __restrict__ cls_w, const float* __restrict__ cls_b,
    float* __restrict__ logits, float* __restrict__ dout)
{
    const int lane = threadIdx.x & 63;
    const int wid  = threadIdx.x >> 6;
    const int pos  = blockIdx.x * 4 + wid;   // 0..32767
    const int b = pos >> 9;
    const int t = pos & 511;

    float4 v0 = *(const float4*)&hf[((size_t)t * 64 + b) * 256 + lane * 4];
    float4 v1 = *(const float4*)&hb[((size_t)t * 64 + b) * 256 + lane * 4];
    float x[8] = {v0.x, v0.y, v0.z, v0.w, v1.x, v1.y, v1.z, v1.w};

    float s = 0.f;
    #pragma unroll
    for (int i = 0; i < 8; ++i) s += x[i];
    #pragma unroll
    for (int off = 32; off > 0; off >>= 1) s += __shfl_xor(s, off, 64);
    float mu = s * (1.f / 512.f);

    float d[8];
    float sq = 0.f;
    #pragma unroll
    for (int i = 0; i < 8; ++i) { d[i] = x[i] - mu; sq += d[i] * d[i]; }
    #pragma unroll
    for (int off = 32; off > 0; off >>= 1) sq += __shfl_xor(sq, off, 64);
    float rs = 1.f / sqrtf(sq * (1.f / 512.f) + 1e-5f);

    float4 g0  = *(const float4*)&gamma[lane * 4];
    float4 g1  = *(const float4*)&gamma[256 + lane * 4];
    float4 be0 = *(const float4*)&beta[lane * 4];
    float4 be1 = *(const float4*)&beta[256 + lane * 4];
    float y[8];
    y[0] = d[0] * rs * g0.x + be0.x; y[1] = d[1] * rs * g0.y + be0.y;
    y[2] = d[2] * rs * g0.z + be0.z; y[3] = d[3] * rs * g0.w + be0.w;
    y[4] = d[4] * rs * g1.x + be1.x; y[5] = d[5] * rs * g1.y + be1.y;
    y[6] = d[6] * rs * g1.z + be1.z; y[7] = d[7] * rs * g1.w + be1.w;

    float lgt[9];
    #pragma unroll
    for (int c = 0; c < 9; ++c) {
        float4 w0 = *(const float4*)&cls_w[c * 512 + lane * 4];
        float4 w1 = *(const float4*)&cls_w[c * 512 + 256 + lane * 4];
        float p = y[0] * w0.x + y[1] * w0.y + y[2] * w0.z + y[3] * w0.w
                + y[4] * w1.x + y[5] * w1.y + y[6] * w1.z + y[7] * w1.w;
        #pragma unroll
        for (int off = 32; off > 0; off >>= 1) p += __shfl_xor(p, off, 64);
        lgt[c] = p + cls_b[c];
    }
    if (lane == 0) {
        int bestc = 0;
        float bestv = lgt[0];
        #pragma unroll
        for (int c = 1; c < 9; ++c)
            if (lgt[c] > bestv) { bestv = lgt[c]; bestc = c; }  // strict >: first max
        dout[1 + pos] = (float)bestc;
        #pragma unroll
        for (int c = 0; c < 9; ++c) logits[(size_t)pos * 9 + c] = lgt[c];
    }
}

// ---------------------------------------------------------------------------
// Kernel 4: CRF numerator + forward algorithm (logZ). One wave per batch row.
// ---------------------------------------------------------------------------
__global__ __launch_bounds__(64) void crf_kernel(
    const float* __restrict__ logits, const int* __restrict__ label_ids,
    const float* __restrict__ crf_start, const float* __restrict__ crf_end,
    const float* __restrict__ crf_trans, float* __restrict__ llh)
{
    __shared__ float Ts[9][12];
    const int b = blockIdx.x;
    const int lane = threadIdx.x;
    if (lane < 81) Ts[lane / 9][lane % 9] = crf_trans[lane];
    __syncthreads();

    const float* __restrict__ em  = &logits[(size_t)b * 512 * 9];
    const int* __restrict__ tags  = &label_ids[b * 512];

    float part = 0.f;
    for (int t = lane; t < 512; t += 64) {
        int tg = tags[t];
        part += em[t * 9 + tg];
        if (t < 511) part += Ts[tg][tags[t + 1]];
    }
    #pragma unroll
    for (int off = 32; off > 0; off >>= 1) part += __shfl_xor(part, off, 64);
    float numer = part + crf_start[tags[0]] + crf_end[tags[511]];

    const int j = (lane < 9) ? lane : 0;
    float alpha = crf_start[j] + em[j];
    for (int t = 1; t < 512; ++t) {
        float av[9];
        float m = -1e30f;
        #pragma unroll
        for (int i = 0; i < 9; ++i) {
            float ai = __shfl(alpha, i, 64);
            av[i] = ai + Ts[i][j];
            m = fmaxf(m, av[i]);
        }
        float ssum = 0.f;
        #pragma unroll
        for (int i = 0; i < 9; ++i) ssum += expf(av[i] - m);
        alpha = m + logf(ssum) + em[t * 9 + j];
    }
    float v = (lane < 9) ? (alpha + crf_end[j]) : -1e30f;
    float mm = v;
    #pragma unroll
    for (int off = 32; off > 0; off >>= 1) mm = fmaxf(mm, __shfl_xor(mm, off, 64));
    float es = (lane < 9) ? expf(v - mm) : 0.f;
    #pragma unroll
    for (int off = 32; off > 0; off >>= 1) es += __shfl_xor(es, off, 64);
    if (lane == 0) llh[b] = numer - (mm + logf(es));
}

// ---------------------------------------------------------------------------
// Kernel 5: loss = -sum_b llh[b]
// ---------------------------------------------------------------------------
__global__ __launch_bounds__(64) void final_reduce(
    const float* __restrict__ llh, float* __restrict__ dout)
{
    float v = llh[threadIdx.x];
    #pragma unroll
    for (int off = 32; off > 0; off >>= 1) v += __shfl_xor(v, off, 64);
    if (threadIdx.x == 0) dout[0] = -v;
}

// ---------------------------------------------------------------------------
extern "C" void kernel_launch(void* const* d_in, const int* in_sizes, int n_in,
                              void* d_out, int out_size, void* d_ws, size_t ws_size,
                              hipStream_t stream)
{
    const int*   word_ids  = (const int*)d_in[0];
    const int*   label_ids = (const int*)d_in[1];
    const float* embed     = (const float*)d_in[2];
    const float* w_ih_f    = (const float*)d_in[3];
    const float* w_hh_f    = (const float*)d_in[4];
    const float* b_f       = (const float*)d_in[5];
    const float* w_ih_b    = (const float*)d_in[6];
    const float* w_hh_b    = (const float*)d_in[7];
    const float* b_b       = (const float*)d_in[8];
    const float* ln_gamma  = (const float*)d_in[9];
    const float* ln_beta   = (const float*)d_in[10];
    const float* cls_w     = (const float*)d_in[11];
    const float* cls_b     = (const float*)d_in[12];
    const float* crf_start = (const float*)d_in[13];
    const float* crf_end   = (const float*)d_in[14];
    const float* crf_trans = (const float*)d_in[15];

    char* w = (char*)d_ws;
    auto alloc = [&](size_t bytes) -> char* {
        char* p = w; w += (bytes + 255) & ~(size_t)255; return p;
    };
    float* hf      = (float*)alloc((size_t)8388608 * 4);   // [512][64][256]
    float* hb      = (float*)alloc((size_t)8388608 * 4);
    float* logits  = (float*)alloc((size_t)294912 * 4);    // [B*T][9]
    float* state_c = (float*)alloc((size_t)32768 * 4);     // [dir][64][256]
    float* state_h = (float*)alloc((size_t)32768 * 4);
    float* llh     = (float*)alloc((size_t)64 * 4);
    size_t fixed   = (size_t)(w - (char*)d_ws);

    // choose largest time-chunk L whose bf16 X buffers fit (L=512 expected)
    int L = 512;
    while (L > 32 && fixed + (size_t)L * 262144 > ws_size) L >>= 1;
    unsigned short* XF = (unsigned short*)alloc((size_t)L * 65536 * 2);  // [L][64][1024] bf16
    unsigned short* XB = (unsigned short*)alloc((size_t)L * 65536 * 2);
    int lgL = 31 - __builtin_clz((unsigned)L);

    for (int t0 = 0; t0 < 512; t0 += L) {
        proj_kernel<<<dim3(L, 2), 256, 0, stream>>>(
            word_ids, embed, w_ih_f, b_f, w_ih_b, b_b, XF, XB, t0, lgL);
        lstm_scan<<<64, 512, 0, stream>>>(
            XF, XB, w_hh_f, w_hh_b, hf, hb, state_c, state_h, t0, t0 + L);
    }
    ln_cls_kernel<<<8192, 256, 0, stream>>>(
        hf, hb, ln_gamma, ln_beta, cls_w, cls_b, logits, (float*)d_out);
    crf_kernel<<<64, 64, 0, stream>>>(
        logits, label_ids, crf_start, crf_end, crf_trans, llh);
    final_reduce<<<1, 64, 0, stream>>>(llh, (float*)d_out);
}